// Round 1
// baseline (386.162 us; speedup 1.0000x reference)
//
#include <hip/hip_runtime.h>
#include <hip/hip_fp16.h>

#define C  64
#define C8 8
#define EPSV 1e-5f
// k = int(0.6*64) = 38 -> threshold = 38th largest = ascending index 26

__device__ __forceinline__ float silu_f(float v) {
    return v * (1.f / (1.f + __expf(-v)));
}

// LDS layout for y1s: [c][256 fp16] with chunk-XOR swizzle:
//   element (c, loc) lives at  c*256 + (loc ^ ((c&7)*8))
// Phase-1 writes: 8 consecutive loc (aligned) for fixed c -> one 16-B chunk ->
//   ds_write_b128; per 16-lane group each 4-bank range gets 2 lanes (free).
// Phase-2 reads: c uniform across lanes, loc=lane -> conflict-free.
//
// x is NOT staged in LDS anymore: phase 2 / epilogue read it from global
// (fixed c, consecutive lanes -> fully coalesced 256B; L2/L3-warm since
// phase 1 just fetched those lines). This halves LDS -> 4 blocks/CU.
__global__ __launch_bounds__(256, 4) void fused_kernel(
    const float* __restrict__ x, const float* __restrict__ w_dw,
    const float* __restrict__ g1, const float* __restrict__ be1,
    const float* __restrict__ mu1, const float* __restrict__ va1,
    const float* __restrict__ w1, const float* __restrict__ b1,
    const float* __restrict__ g2, const float* __restrict__ be2,
    const float* __restrict__ mu2, const float* __restrict__ va2,
    const float* __restrict__ w2, const float* __restrict__ b2,
    const float* __restrict__ alphap, float* __restrict__ out)
{
    __shared__ __align__(16) __half y1s[C * 256];   // 32 KB
    __shared__ float wt[C * 25];                    // 6.4 KB, conv weights

    const int blk = blockIdx.x;        // 1024 = b*256 + d*16 + hb
    const int hb = blk & 15;
    const int d  = (blk >> 4) & 15;
    const int b  = blk >> 8;
    const int h0 = hb * 4;
    const int tid = threadIdx.x;

    // stage depthwise weights to LDS (frees ~25 VGPRs in phase 1;
    // read addresses 25c+k mod 32 are conflict-free since gcd(25,32)=1)
    for (int i = tid; i < C * 25; i += 256) wt[i] = w_dw[i];
    __syncthreads();

    // ---------------- phase 1: depthwise conv rows h0..h0+3 -> y1 to LDS
    {
        const int c     = tid >> 2;        // 0..63
        const int strip = tid & 3;
        const int w16   = strip * 16;      // output cols w16..w16+15
        const int q     = w16 >> 2;

        const float scale = g1[c] * rsqrtf(va1[c] + EPSV);
        const float shift = be1[c] - mu1[c] * scale;
        const long xbase = ((long)(b * C + c) * 16 + d) * 4096;

        float acc[4][16];
#pragma unroll
        for (int i = 0; i < 4; ++i)
#pragma unroll
            for (int ow = 0; ow < 16; ++ow) acc[i][ow] = 0.f;

#pragma unroll
        for (int j = 0; j < 8; ++j) {      // input row r = h0 + j - 2
            const int r = h0 + j - 2;
            if (r >= 0 && r < 64) {
                const float4* rowp = (const float4*)(x + xbase + r * 64);
                const float4 z = make_float4(0.f, 0.f, 0.f, 0.f);
                float4 u0 = (q > 0)  ? rowp[q - 1] : z;
                float4 u1 = rowp[q];
                float4 u2 = rowp[q + 1];
                float4 u3 = rowp[q + 2];
                float4 u4 = rowp[q + 3];
                float4 u5 = (q < 12) ? rowp[q + 4] : z;
                // vals[v] = x[row r, col w16 - 4 + v]
                float vals[24] = {u0.x,u0.y,u0.z,u0.w, u1.x,u1.y,u1.z,u1.w,
                                  u2.x,u2.y,u2.z,u2.w, u3.x,u3.y,u3.z,u3.w,
                                  u4.x,u4.y,u4.z,u4.w, u5.x,u5.y,u5.z,u5.w};
#pragma unroll
                for (int i = 0; i < 4; ++i) {
                    if (i <= j && (j - i) <= 4) {   // kernel row kr = j - i
                        const int kr = j - i;
                        const float* wrow = &wt[c * 25 + kr * 5];
#pragma unroll
                        for (int kc = 0; kc < 5; ++kc) {
                            const float kw = wrow[kc];
#pragma unroll
                            for (int ow = 0; ow < 16; ++ow)
                                acc[i][ow] += kw * vals[ow + kc + 2];
                        }
                    }
                }
            }
        }
        const int csw = (c & 7);           // chunk-XOR term
#pragma unroll
        for (int i = 0; i < 4; ++i) {
            float o[16];
#pragma unroll
            for (int ow = 0; ow < 16; ++ow)
                o[ow] = silu_f(acc[i][ow] * scale + shift);
            const int chunkbase = i * 8 + 2 * strip;
#pragma unroll
            for (int t = 0; t < 2; ++t) {
                const int p = (chunkbase + t) ^ csw;
                union { __half2 h[4]; float4 f; } u;
#pragma unroll
                for (int m = 0; m < 4; ++m)
                    u.h[m] = __floats2half2_rn(o[t * 8 + 2 * m], o[t * 8 + 2 * m + 1]);
                *(float4*)&y1s[c * 256 + p * 8] = u.f;
            }
        }
    }
    __syncthreads();

    // ---------------- phase 2: pw1 + BN2 + SiLU + pw2, attn, top-k, epilogue
    {
        const int loc = tid;
        const int rg  = d * 4096 + (h0 + (tid >> 6)) * 64 + (tid & 63);
        const long xoff = (long)b * (C * 65536) + rg;   // x and out share layout

        // pw1 from global x (coalesced per wave; L2/L3-warm from phase 1)
        float s1[C8];
#pragma unroll
        for (int o = 0; o < C8; ++o) s1[o] = 0.f;
#pragma unroll
        for (int c = 0; c < C; ++c) {
            const float xc = x[xoff + (long)c * 65536];
#pragma unroll
            for (int o = 0; o < C8; ++o) s1[o] += w1[o * C + c] * xc;
        }
        float hh[C8];
#pragma unroll
        for (int o = 0; o < C8; ++o) {
            const float sc = g2[o] * rsqrtf(va2[o] + EPSV);
            hh[o] = silu_f((s1[o] + b1[o] - mu2[o]) * sc + be2[o]);
        }

        // attn values into sort scratch only; epilogue recomputes exactly
        // the same expression from hh[] (bitwise identical), freeing a[64].
        float t[C];
#pragma unroll
        for (int c = 0; c < C; ++c) {
            const float y1v = __half2float(y1s[c * 256 + (loc ^ ((c & 7) << 3))]);
            float y2 = b2[c];
#pragma unroll
            for (int o = 0; o < C8; ++o) y2 += w2[c * C8 + o] * hh[o];
            t[c] = y1v * y2;
        }

        // in-register bitonic sort (ascending) of 64 values
#pragma unroll
        for (int k = 2; k <= 64; k <<= 1) {
#pragma unroll
            for (int j = k >> 1; j > 0; j >>= 1) {
#pragma unroll
                for (int i = 0; i < 64; ++i) {
                    const int l = i ^ j;
                    if (l > i) {
                        const float u = t[i], v = t[l];
                        const float mn = fminf(u, v), mx = fmaxf(u, v);
                        if ((i & k) == 0) { t[i] = mn; t[l] = mx; }
                        else              { t[i] = mx; t[l] = mn; }
                    }
                }
            }
        }
        const float thr = t[26];          // 38th largest of 64
        const float alpha = alphap[0];

        float* op = out + xoff;

        // epilogue: recompute attn from hh[] + y1s; x re-read from global
        // (L1/L2-hot); only coalesced loads/stores go global.
#pragma unroll
        for (int c = 0; c < C; ++c) {
            const float y1v = __half2float(y1s[c * 256 + (loc ^ ((c & 7) << 3))]);
            float y2 = b2[c];
#pragma unroll
            for (int o = 0; o < C8; ++o) y2 += w2[c * C8 + o] * hh[o];
            const float av = y1v * y2;
            const float xc = x[xoff + (long)c * 65536];
            op[(long)c * 65536] = xc + ((av >= thr) ? alpha * av : 0.f);
        }
    }
}

extern "C" void kernel_launch(void* const* d_in, const int* in_sizes, int n_in,
                              void* d_out, int out_size, void* d_ws, size_t ws_size,
                              hipStream_t stream) {
    const float* x    = (const float*)d_in[0];
    const float* w_dw = (const float*)d_in[1];
    const float* g1   = (const float*)d_in[2];
    const float* be1  = (const float*)d_in[3];
    const float* mu1  = (const float*)d_in[4];
    const float* va1  = (const float*)d_in[5];
    const float* w1   = (const float*)d_in[6];
    const float* b1   = (const float*)d_in[7];
    const float* g2   = (const float*)d_in[8];
    const float* be2  = (const float*)d_in[9];
    const float* mu2  = (const float*)d_in[10];
    const float* va2  = (const float*)d_in[11];
    const float* w2   = (const float*)d_in[12];
    const float* b2   = (const float*)d_in[13];
    const float* alp  = (const float*)d_in[14];
    float* out = (float*)d_out;

    // grid: b(4) x d(16) x h-band(16) = 1024 blocks = exactly 4 blocks/CU
    fused_kernel<<<1024, 256, 0, stream>>>(
        x, w_dw, g1, be1, mu1, va1, w1, b1, g2, be2, mu2, va2, w2, b2, alp, out);
}

// Round 2
// 347.251 us; speedup vs baseline: 1.1121x; 1.1121x over previous
//
#include <hip/hip_runtime.h>
#include <hip/hip_fp16.h>

#define C  64
#define C8 8
#define EPSV 1e-5f
// k = int(0.6*64) = 38 -> threshold = 38th largest = ascending index 26

__device__ __forceinline__ float silu_f(float v) {
    return v * (1.f / (1.f + __expf(-v)));
}

// LDS layout for y1s: [c][256 fp16] with chunk-XOR swizzle:
//   element (c, loc) lives at  c*256 + (loc ^ ((c&7)*8))
// Phase-1 writes: 8 consecutive loc (aligned) for fixed c -> one 16-B chunk ->
//   ds_write_b128; per 16-lane group each 4-bank range gets 2 lanes (free).
// Phase-2 reads: c uniform across lanes, loc=lane -> conflict-free.
//
// x is NOT staged in LDS: phase 2 / epilogue read it from global
// (fixed c, consecutive lanes -> fully coalesced 256B; L2/L3-warm since
// phase 1 just fetched those lines). LDS = 38.4 KB.
//
// launch_bounds(256,3): VGPR cap 170. (256,4)=cap 128 cliff-spilled the
// sort array to scratch (round 1: +745 MB HBM, 2.4x slower). At 170 the
// ~110-120 live set fits; occupancy 2 -> 3 blocks/CU (12 waves/CU).
__global__ __launch_bounds__(256, 3) void fused_kernel(
    const float* __restrict__ x, const float* __restrict__ w_dw,
    const float* __restrict__ g1, const float* __restrict__ be1,
    const float* __restrict__ mu1, const float* __restrict__ va1,
    const float* __restrict__ w1, const float* __restrict__ b1,
    const float* __restrict__ g2, const float* __restrict__ be2,
    const float* __restrict__ mu2, const float* __restrict__ va2,
    const float* __restrict__ w2, const float* __restrict__ b2,
    const float* __restrict__ alphap, float* __restrict__ out)
{
    __shared__ __align__(16) __half y1s[C * 256];   // 32 KB
    __shared__ float wt[C * 25];                    // 6.4 KB, conv weights

    const int blk = blockIdx.x;        // 1024 = b*256 + d*16 + hb
    const int hb = blk & 15;
    const int d  = (blk >> 4) & 15;
    const int b  = blk >> 8;
    const int h0 = hb * 4;
    const int tid = threadIdx.x;

    // stage depthwise weights to LDS (frees ~25 VGPRs in phase 1;
    // read addresses 25c+k mod 32 are conflict-free since gcd(25,32)=1)
    for (int i = tid; i < C * 25; i += 256) wt[i] = w_dw[i];
    __syncthreads();

    // ---------------- phase 1: depthwise conv rows h0..h0+3 -> y1 to LDS
    {
        const int c     = tid >> 2;        // 0..63
        const int strip = tid & 3;
        const int w16   = strip * 16;      // output cols w16..w16+15
        const int q     = w16 >> 2;

        const float scale = g1[c] * rsqrtf(va1[c] + EPSV);
        const float shift = be1[c] - mu1[c] * scale;
        const long xbase = ((long)(b * C + c) * 16 + d) * 4096;

        float acc[4][16];
#pragma unroll
        for (int i = 0; i < 4; ++i)
#pragma unroll
            for (int ow = 0; ow < 16; ++ow) acc[i][ow] = 0.f;

#pragma unroll
        for (int j = 0; j < 8; ++j) {      // input row r = h0 + j - 2
            const int r = h0 + j - 2;
            if (r >= 0 && r < 64) {
                const float4* rowp = (const float4*)(x + xbase + r * 64);
                const float4 z = make_float4(0.f, 0.f, 0.f, 0.f);
                float4 u0 = (q > 0)  ? rowp[q - 1] : z;
                float4 u1 = rowp[q];
                float4 u2 = rowp[q + 1];
                float4 u3 = rowp[q + 2];
                float4 u4 = rowp[q + 3];
                float4 u5 = (q < 12) ? rowp[q + 4] : z;
                // vals[v] = x[row r, col w16 - 4 + v]
                float vals[24] = {u0.x,u0.y,u0.z,u0.w, u1.x,u1.y,u1.z,u1.w,
                                  u2.x,u2.y,u2.z,u2.w, u3.x,u3.y,u3.z,u3.w,
                                  u4.x,u4.y,u4.z,u4.w, u5.x,u5.y,u5.z,u5.w};
#pragma unroll
                for (int i = 0; i < 4; ++i) {
                    if (i <= j && (j - i) <= 4) {   // kernel row kr = j - i
                        const int kr = j - i;
                        const float* wrow = &wt[c * 25 + kr * 5];
#pragma unroll
                        for (int kc = 0; kc < 5; ++kc) {
                            const float kw = wrow[kc];
#pragma unroll
                            for (int ow = 0; ow < 16; ++ow)
                                acc[i][ow] += kw * vals[ow + kc + 2];
                        }
                    }
                }
            }
        }
        const int csw = (c & 7);           // chunk-XOR term
#pragma unroll
        for (int i = 0; i < 4; ++i) {
            float o[16];
#pragma unroll
            for (int ow = 0; ow < 16; ++ow)
                o[ow] = silu_f(acc[i][ow] * scale + shift);
            const int chunkbase = i * 8 + 2 * strip;
#pragma unroll
            for (int t = 0; t < 2; ++t) {
                const int p = (chunkbase + t) ^ csw;
                union { __half2 h[4]; float4 f; } u;
#pragma unroll
                for (int m = 0; m < 4; ++m)
                    u.h[m] = __floats2half2_rn(o[t * 8 + 2 * m], o[t * 8 + 2 * m + 1]);
                *(float4*)&y1s[c * 256 + p * 8] = u.f;
            }
        }
    }
    __syncthreads();

    // ---------------- phase 2: pw1 + BN2 + SiLU + pw2, attn, top-k, epilogue
    {
        const int loc = tid;
        const int rg  = d * 4096 + (h0 + (tid >> 6)) * 64 + (tid & 63);
        const long xoff = (long)b * (C * 65536) + rg;   // x and out share layout

        // pw1 from global x (coalesced per wave; L2/L3-warm from phase 1)
        float s1[C8];
#pragma unroll
        for (int o = 0; o < C8; ++o) s1[o] = 0.f;
#pragma unroll
        for (int c = 0; c < C; ++c) {
            const float xc = x[xoff + (long)c * 65536];
#pragma unroll
            for (int o = 0; o < C8; ++o) s1[o] += w1[o * C + c] * xc;
        }
        float hh[C8];
#pragma unroll
        for (int o = 0; o < C8; ++o) {
            const float sc = g2[o] * rsqrtf(va2[o] + EPSV);
            hh[o] = silu_f((s1[o] + b1[o] - mu2[o]) * sc + be2[o]);
        }

        // attn values into sort scratch only; epilogue recomputes exactly
        // the same expression from hh[] (bitwise identical), freeing a[64].
        float t[C];
#pragma unroll
        for (int c = 0; c < C; ++c) {
            const float y1v = __half2float(y1s[c * 256 + (loc ^ ((c & 7) << 3))]);
            float y2 = b2[c];
#pragma unroll
            for (int o = 0; o < C8; ++o) y2 += w2[c * C8 + o] * hh[o];
            t[c] = y1v * y2;
        }

        // in-register bitonic sort (ascending) of 64 values
#pragma unroll
        for (int k = 2; k <= 64; k <<= 1) {
#pragma unroll
            for (int j = k >> 1; j > 0; j >>= 1) {
#pragma unroll
                for (int i = 0; i < 64; ++i) {
                    const int l = i ^ j;
                    if (l > i) {
                        const float u = t[i], v = t[l];
                        const float mn = fminf(u, v), mx = fmaxf(u, v);
                        if ((i & k) == 0) { t[i] = mn; t[l] = mx; }
                        else              { t[i] = mx; t[l] = mn; }
                    }
                }
            }
        }
        const float thr = t[26];          // 38th largest of 64
        const float alpha = alphap[0];

        float* op = out + xoff;

        // epilogue: recompute attn from hh[] + y1s; x re-read from global
        // (L2/L3-hot); only coalesced loads/stores go global.
#pragma unroll
        for (int c = 0; c < C; ++c) {
            const float y1v = __half2float(y1s[c * 256 + (loc ^ ((c & 7) << 3))]);
            float y2 = b2[c];
#pragma unroll
            for (int o = 0; o < C8; ++o) y2 += w2[c * C8 + o] * hh[o];
            const float av = y1v * y2;
            const float xc = x[xoff + (long)c * 65536];
            op[(long)c * 65536] = xc + ((av >= thr) ? alpha * av : 0.f);
        }
    }
}

extern "C" void kernel_launch(void* const* d_in, const int* in_sizes, int n_in,
                              void* d_out, int out_size, void* d_ws, size_t ws_size,
                              hipStream_t stream) {
    const float* x    = (const float*)d_in[0];
    const float* w_dw = (const float*)d_in[1];
    const float* g1   = (const float*)d_in[2];
    const float* be1  = (const float*)d_in[3];
    const float* mu1  = (const float*)d_in[4];
    const float* va1  = (const float*)d_in[5];
    const float* w1   = (const float*)d_in[6];
    const float* b1   = (const float*)d_in[7];
    const float* g2   = (const float*)d_in[8];
    const float* be2  = (const float*)d_in[9];
    const float* mu2  = (const float*)d_in[10];
    const float* va2  = (const float*)d_in[11];
    const float* w2   = (const float*)d_in[12];
    const float* b2   = (const float*)d_in[13];
    const float* alp  = (const float*)d_in[14];
    float* out = (float*)d_out;

    // grid: b(4) x d(16) x h-band(16) = 1024 blocks
    fused_kernel<<<1024, 256, 0, stream>>>(
        x, w_dw, g1, be1, mu1, va1, w1, b1, g2, be2, mu2, va2, w2, b2, alp, out);
}

// Round 4
// 340.375 us; speedup vs baseline: 1.1345x; 1.0202x over previous
//
#include <hip/hip_runtime.h>
#include <hip/hip_fp16.h>

#define C  64
#define C8 8
#define EPSV 1e-5f
// k = int(0.6*64) = 38 -> threshold = 38th largest = ascending index 26 of 64

__device__ __forceinline__ float silu_f(float v) {
    return v * (1.f / (1.f + __expf(-v)));
}

// Lane-pair decomposition: block = 256 threads covers 2 rows (128 locations);
// lanes 2i/2i+1 share location i, each owning 32 of the 64 channels.
//   - halves the sort array (t[32] not t[64]) -> live set ~85 VGPRs
//   - __launch_bounds__(256,2): empirically cap = 256/arg2 = 128 VGPRs
//     ((256,4)->64, (256,3)->84 both cliff-spilled; 128 fits, 16 waves/CU)
//   - top-k: per-lane 32-sort + 1 cross-lane bitonic CE (lower half of the
//     merged 64 is bitonic, same multiset in both lanes) + 5-stage clean.
//     Exact k-th largest, bitwise identical in both lanes.
//
// LDS y1s: [c][128 fp16], chunk-XOR swizzle: elem (c,loc) at
//   c*128 + (loc ^ ((c&7)*8)).  16 KB + 6.4 KB wt = 22.4 KB.
// x is read from global in phase 2 / epilogue (coalesced, L2/L3-warm).
__global__ __launch_bounds__(256, 2) void fused_kernel(
    const float* __restrict__ x, const float* __restrict__ w_dw,
    const float* __restrict__ g1, const float* __restrict__ be1,
    const float* __restrict__ mu1, const float* __restrict__ va1,
    const float* __restrict__ w1, const float* __restrict__ b1,
    const float* __restrict__ g2, const float* __restrict__ be2,
    const float* __restrict__ mu2, const float* __restrict__ va2,
    const float* __restrict__ w2, const float* __restrict__ b2,
    const float* __restrict__ alphap, float* __restrict__ out)
{
    __shared__ __align__(16) __half y1s[C * 128];   // 16 KB
    __shared__ float wt[C * 25];                    // 6.4 KB, conv weights

    const int blk = blockIdx.x;        // 2048 = b*512 + d*32 + hp
    const int hp = blk & 31;
    const int d  = (blk >> 5) & 15;
    const int b  = blk >> 9;
    const int h0 = hp * 2;             // output rows h0, h0+1
    const int tid = threadIdx.x;

    for (int i = tid; i < C * 25; i += 256) wt[i] = w_dw[i];
    __syncthreads();

    // ---------------- phase 1: depthwise conv rows h0..h0+1 -> y1 to LDS
    {
        const int c     = tid >> 2;        // 0..63
        const int strip = tid & 3;
        const int w16   = strip * 16;      // output cols w16..w16+15
        const int q     = w16 >> 2;

        const float scale = g1[c] * rsqrtf(va1[c] + EPSV);
        const float shift = be1[c] - mu1[c] * scale;
        const long xbase = ((long)(b * C + c) * 16 + d) * 4096;

        float acc[2][16];
#pragma unroll
        for (int i = 0; i < 2; ++i)
#pragma unroll
            for (int ow = 0; ow < 16; ++ow) acc[i][ow] = 0.f;

#pragma unroll
        for (int j = 0; j < 6; ++j) {      // input row r = h0 + j - 2
            const int r = h0 + j - 2;
            if (r >= 0 && r < 64) {
                const float4* rowp = (const float4*)(x + xbase + r * 64);
                const float4 z = make_float4(0.f, 0.f, 0.f, 0.f);
                float4 u0 = (q > 0)  ? rowp[q - 1] : z;
                float4 u1 = rowp[q];
                float4 u2 = rowp[q + 1];
                float4 u3 = rowp[q + 2];
                float4 u4 = rowp[q + 3];
                float4 u5 = (q < 12) ? rowp[q + 4] : z;
                // vals[v] = x[row r, col w16 - 4 + v]
                float vals[24] = {u0.x,u0.y,u0.z,u0.w, u1.x,u1.y,u1.z,u1.w,
                                  u2.x,u2.y,u2.z,u2.w, u3.x,u3.y,u3.z,u3.w,
                                  u4.x,u4.y,u4.z,u4.w, u5.x,u5.y,u5.z,u5.w};
#pragma unroll
                for (int i = 0; i < 2; ++i) {
                    if (i <= j && (j - i) <= 4) {   // kernel row kr = j - i
                        const int kr = j - i;
                        const float* wrow = &wt[c * 25 + kr * 5];
#pragma unroll
                        for (int kc = 0; kc < 5; ++kc) {
                            const float kw = wrow[kc];
#pragma unroll
                            for (int ow = 0; ow < 16; ++ow)
                                acc[i][ow] += kw * vals[ow + kc + 2];
                        }
                    }
                }
            }
        }
        const int csw = (c & 7);           // chunk-XOR term
#pragma unroll
        for (int i = 0; i < 2; ++i) {
            float o[16];
#pragma unroll
            for (int ow = 0; ow < 16; ++ow)
                o[ow] = silu_f(acc[i][ow] * scale + shift);
            const int chunkbase = i * 8 + 2 * strip;
#pragma unroll
            for (int t = 0; t < 2; ++t) {
                const int p = (chunkbase + t) ^ csw;
                union { __half2 h[4]; float4 f; } u;
#pragma unroll
                for (int m = 0; m < 4; ++m)
                    u.h[m] = __floats2half2_rn(o[t * 8 + 2 * m], o[t * 8 + 2 * m + 1]);
                *(float4*)&y1s[c * 128 + p * 8] = u.f;
            }
        }
    }
    __syncthreads();

    // ---------------- phase 2: pw1 + BN2 + SiLU + pw2, attn, top-k, epilogue
    {
        const int loc  = tid >> 1;         // 0..127 (2 rows x 64 cols)
        const int half = tid & 1;          // channel half owned by this lane
        const int ch0  = half * 32;
        const int rg   = d * 4096 + (h0 + (loc >> 6)) * 64 + (loc & 63);
        const long xoff = (long)b * (C * 65536) + rg;   // x/out share layout

        // pw1: each lane sums its 32 channels, one shuffle round completes it
        float s1[C8];
#pragma unroll
        for (int o = 0; o < C8; ++o) s1[o] = 0.f;
#pragma unroll
        for (int cc = 0; cc < 32; ++cc) {
            const int ch = ch0 + cc;
            const float xc = x[xoff + (long)ch * 65536];
#pragma unroll
            for (int o = 0; o < C8; ++o) s1[o] += w1[o * C + ch] * xc;
        }
#pragma unroll
        for (int o = 0; o < C8; ++o) s1[o] += __shfl_xor(s1[o], 1);
        float hh[C8];
#pragma unroll
        for (int o = 0; o < C8; ++o) {
            const float sc = g2[o] * rsqrtf(va2[o] + EPSV);
            hh[o] = silu_f((s1[o] + b1[o] - mu2[o]) * sc + be2[o]);
        }

        // attn values for this lane's 32 channels
        float t[32];
#pragma unroll
        for (int cc = 0; cc < 32; ++cc) {
            const int ch = ch0 + cc;
            const float y1v = __half2float(y1s[ch * 128 + (loc ^ ((ch & 7) << 3))]);
            float y2 = b2[ch];
#pragma unroll
            for (int o = 0; o < C8; ++o) y2 += w2[ch * C8 + o] * hh[o];
            t[cc] = y1v * y2;
        }

        // per-lane bitonic sort (ascending) of 32 values
#pragma unroll
        for (int k = 2; k <= 32; k <<= 1) {
#pragma unroll
            for (int j = k >> 1; j > 0; j >>= 1) {
#pragma unroll
                for (int i = 0; i < 32; ++i) {
                    const int l = i ^ j;
                    if (l > i) {
                        const float u = t[i], v = t[l];
                        const float mn = fminf(u, v), mx = fmaxf(u, v);
                        if ((i & k) == 0) { t[i] = mn; t[l] = mx; }
                        else              { t[i] = mx; t[l] = mn; }
                    }
                }
            }
        }
        // cross-lane merge: lower 32 of merged 64 (bitonic, same multiset in
        // both lanes). A asc (lane even) ++ rev(B asc) (lane odd) is bitonic;
        // CE at distance 32 keeps mins -> lower half.  In-place by (i,31-i).
#pragma unroll
        for (int i = 0; i < 16; ++i) {
            const float oi = __shfl_xor(t[31 - i], 1);
            const float oj = __shfl_xor(t[i], 1);
            const float ti = t[i], tj = t[31 - i];
            t[i]      = fminf(ti, oi);
            t[31 - i] = fminf(tj, oj);
        }
        // bitonic clean -> ascending; index 26 = 38th largest of the 64
#pragma unroll
        for (int j = 16; j > 0; j >>= 1) {
#pragma unroll
            for (int i = 0; i < 32; ++i) {
                const int l = i ^ j;
                if (l > i) {
                    const float u = t[i], v = t[l];
                    t[i] = fminf(u, v); t[l] = fmaxf(u, v);
                }
            }
        }
        const float thr = t[26];
        const float alpha = alphap[0];

        float* op = out + xoff;

        // epilogue: recompute attn from hh[] + y1s (bitwise identical to the
        // sorted values); x re-read from global (L2/L3-hot); coalesced stores
#pragma unroll
        for (int cc = 0; cc < 32; ++cc) {
            const int ch = ch0 + cc;
            const float y1v = __half2float(y1s[ch * 128 + (loc ^ ((ch & 7) << 3))]);
            float y2 = b2[ch];
#pragma unroll
            for (int o = 0; o < C8; ++o) y2 += w2[ch * C8 + o] * hh[o];
            const float av = y1v * y2;
            const float xc = x[xoff + (long)ch * 65536];
            op[(long)ch * 65536] = xc + ((av >= thr) ? alpha * av : 0.f);
        }
    }
}

extern "C" void kernel_launch(void* const* d_in, const int* in_sizes, int n_in,
                              void* d_out, int out_size, void* d_ws, size_t ws_size,
                              hipStream_t stream) {
    const float* x    = (const float*)d_in[0];
    const float* w_dw = (const float*)d_in[1];
    const float* g1   = (const float*)d_in[2];
    const float* be1  = (const float*)d_in[3];
    const float* mu1  = (const float*)d_in[4];
    const float* va1  = (const float*)d_in[5];
    const float* w1   = (const float*)d_in[6];
    const float* b1   = (const float*)d_in[7];
    const float* g2   = (const float*)d_in[8];
    const float* be2  = (const float*)d_in[9];
    const float* mu2  = (const float*)d_in[10];
    const float* va2  = (const float*)d_in[11];
    const float* w2   = (const float*)d_in[12];
    const float* b2   = (const float*)d_in[13];
    const float* alp  = (const float*)d_in[14];
    float* out = (float*)d_out;

    // grid: b(4) x d(16) x row-pair(32) = 2048 blocks
    fused_kernel<<<2048, 256, 0, stream>>>(
        x, w_dw, g1, be1, mu1, va1, w1, b1, g2, be2, mu2, va2, w2, b2, alp, out);
}

// Round 5
// 327.838 us; speedup vs baseline: 1.1779x; 1.0382x over previous
//
#include <hip/hip_runtime.h>
#include <hip/hip_fp16.h>

#define C  64
#define C8 8
#define EPSV 1e-5f
// k = int(0.6*64) = 38 -> threshold = 38th largest = ascending index 26 of 64

__device__ __forceinline__ float silu_f(float v) {
    return v * (1.f / (1.f + __expf(-v)));
}
// channel swizzle for [ch][64] fp16 LDS tiles: chunk-XOR term.
// Uses ch^(ch>>3) so the four phase-2 channel quarters (ch = q*16+cc,
// identical mod 8) still get distinct swizzles -> conflict-free reads.
__device__ __forceinline__ int swz7(int ch) { return (ch ^ (ch >> 3)) & 7; }

// 4-lane-group decomposition: block = 1 output row = 64 locations;
// lanes 4i..4i+3 share location i, each owning 16 of the 64 channels.
//   - sort array t[16]; phase-1 acc[16]  -> live set ~80 VGPRs, real
//     headroom under the (256,2) => 128-VGPR cap (round-4's t[32]
//     structure needed ~142 and spilled 14 regs at the same cap).
//   - x staged in LDS fp16 (round-0 discipline): HBM traffic = read x
//     once + write out once. Phase-2 global-x reads (rounds 2-4) missed
//     L2 and inflated FETCH by ~75 MB.
//   - exact top-k: per-lane bitonic-16, distributed bitonic merge across
//     the 4-lane group. Lanes {0,2} end with ranks 0-15, {1,3} with
//     ranks 16-31 of the 64; rank 26 = odd lanes' [10].
__global__ __launch_bounds__(256, 2) void fused_kernel(
    const float* __restrict__ x, const float* __restrict__ w_dw,
    const float* __restrict__ g1, const float* __restrict__ be1,
    const float* __restrict__ mu1, const float* __restrict__ va1,
    const float* __restrict__ w1, const float* __restrict__ b1,
    const float* __restrict__ g2, const float* __restrict__ be2,
    const float* __restrict__ mu2, const float* __restrict__ va2,
    const float* __restrict__ w2, const float* __restrict__ b2,
    const float* __restrict__ alphap, float* __restrict__ out)
{
    __shared__ __align__(16) __half xs [C * 64];   // 8 KB, x row h
    __shared__ __align__(16) __half y1s[C * 64];   // 8 KB, conv out row h
    __shared__ float wt[C * 25];                   // 6.4 KB, conv weights

    const int blk = blockIdx.x;        // 4096 = b*1024 + d*64 + h
    const int h   = blk & 63;
    const int d   = (blk >> 6) & 15;
    const int b   = blk >> 10;
    const int tid = threadIdx.x;

    for (int i = tid; i < C * 25; i += 256) wt[i] = w_dw[i];
    __syncthreads();

    // ---------------- phase 1: depthwise conv row h -> y1s; stage x row -> xs
    {
        const int c     = tid >> 2;        // 0..63
        const int strip = tid & 3;
        const int w16   = strip * 16;      // output cols w16..w16+15
        const int q     = w16 >> 2;
        const int s7    = swz7(c);

        const float scale = g1[c] * rsqrtf(va1[c] + EPSV);
        const float shift = be1[c] - mu1[c] * scale;
        const long xbase = ((long)(b * C + c) * 16 + d) * 4096;

        float acc[16];
#pragma unroll
        for (int ow = 0; ow < 16; ++ow) acc[ow] = 0.f;

#pragma unroll
        for (int kr = 0; kr < 5; ++kr) {   // input row r = h + kr - 2
            const int r = h + kr - 2;
            if (r >= 0 && r < 64) {
                const float4* rowp = (const float4*)(x + xbase + r * 64);
                const float4 z = make_float4(0.f, 0.f, 0.f, 0.f);
                float4 u0 = (q > 0)  ? rowp[q - 1] : z;
                float4 u1 = rowp[q];
                float4 u2 = rowp[q + 1];
                float4 u3 = rowp[q + 2];
                float4 u4 = rowp[q + 3];
                float4 u5 = (q < 12) ? rowp[q + 4] : z;
                // vals[v] = x[row r, col w16 - 4 + v]
                float vals[24] = {u0.x,u0.y,u0.z,u0.w, u1.x,u1.y,u1.z,u1.w,
                                  u2.x,u2.y,u2.z,u2.w, u3.x,u3.y,u3.z,u3.w,
                                  u4.x,u4.y,u4.z,u4.w, u5.x,u5.y,u5.z,u5.w};
                if (kr == 2) {             // r == h: stage x row to xs
#pragma unroll
                    for (int t = 0; t < 2; ++t) {
                        const int p = (2 * strip + t) ^ s7;
                        union { __half2 hx[4]; float4 f; } u;
#pragma unroll
                        for (int m = 0; m < 4; ++m)
                            u.hx[m] = __floats2half2_rn(vals[4 + t * 8 + 2 * m],
                                                        vals[4 + t * 8 + 2 * m + 1]);
                        *(float4*)&xs[c * 64 + p * 8] = u.f;
                    }
                }
                const float* wrow = &wt[c * 25 + kr * 5];
#pragma unroll
                for (int kc = 0; kc < 5; ++kc) {
                    const float kw = wrow[kc];
#pragma unroll
                    for (int ow = 0; ow < 16; ++ow)
                        acc[ow] += kw * vals[ow + kc + 2];
                }
            }
        }
        float o[16];
#pragma unroll
        for (int ow = 0; ow < 16; ++ow)
            o[ow] = silu_f(acc[ow] * scale + shift);
#pragma unroll
        for (int t = 0; t < 2; ++t) {
            const int p = (2 * strip + t) ^ s7;
            union { __half2 hx[4]; float4 f; } u;
#pragma unroll
            for (int m = 0; m < 4; ++m)
                u.hx[m] = __floats2half2_rn(o[t * 8 + 2 * m], o[t * 8 + 2 * m + 1]);
            *(float4*)&y1s[c * 64 + p * 8] = u.f;
        }
    }
    __syncthreads();

    // ---------------- phase 2: pw1 + BN2 + SiLU + pw2, attn, top-k, epilogue
    {
        const int qt  = tid & 3;           // channel quarter owned by lane
        const int loc = tid >> 2;          // 0..63 column within row h
        const int ch0 = qt * 16;
        const bool lo = ((tid & 1) == 0);  // "low" lane of each xor-1 pair

        // pw1: each lane sums its 16 channels; 2 shuffle rounds complete the
        // 64-sum (pairwise-commutative adds -> identical in all 4 lanes)
        float s1[C8];
#pragma unroll
        for (int o = 0; o < C8; ++o) s1[o] = 0.f;
#pragma unroll
        for (int cc = 0; cc < 16; ++cc) {
            const int ch = ch0 + cc;
            const float xc = __half2float(xs[ch * 64 + (loc ^ (swz7(ch) << 3))]);
#pragma unroll
            for (int o = 0; o < C8; ++o) s1[o] += w1[o * C + ch] * xc;
        }
#pragma unroll
        for (int o = 0; o < C8; ++o) s1[o] += __shfl_xor(s1[o], 1);
#pragma unroll
        for (int o = 0; o < C8; ++o) s1[o] += __shfl_xor(s1[o], 2);
        float hh[C8];
#pragma unroll
        for (int o = 0; o < C8; ++o) {
            const float sc = g2[o] * rsqrtf(va2[o] + EPSV);
            hh[o] = silu_f((s1[o] + b1[o] - mu2[o]) * sc + be2[o]);
        }

        // attn values for this lane's 16 channels
        float t[16];
#pragma unroll
        for (int cc = 0; cc < 16; ++cc) {
            const int ch = ch0 + cc;
            const float y1v = __half2float(y1s[ch * 64 + (loc ^ (swz7(ch) << 3))]);
            float y2 = b2[ch];
#pragma unroll
            for (int o = 0; o < C8; ++o) y2 += w2[ch * C8 + o] * hh[o];
            t[cc] = y1v * y2;
        }

        // (1) per-lane bitonic sort ascending of 16
#pragma unroll
        for (int k = 2; k <= 16; k <<= 1) {
#pragma unroll
            for (int j = k >> 1; j > 0; j >>= 1) {
#pragma unroll
                for (int i = 0; i < 16; ++i) {
                    const int l = i ^ j;
                    if (l > i) {
                        const float u = t[i], v = t[l];
                        const float mn = fminf(u, v), mx = fmaxf(u, v);
                        if ((i & k) == 0) { t[i] = mn; t[l] = mx; }
                        else              { t[i] = mx; t[l] = mn; }
                    }
                }
            }
        }
        // (2) xor-1 pair merge: even lane -> ranks 0-15 of pair, odd -> 16-31.
        // CE pairs (A[i], B[15-i]); process (i,15-i) together so shuffles see
        // pre-update values.
#pragma unroll
        for (int i = 0; i < 8; ++i) {
            const float a  = t[i], bb = t[15 - i];
            const float pa = __shfl_xor(a, 1);    // partner's t[i]
            const float pb = __shfl_xor(bb, 1);   // partner's t[15-i]
            if (lo) { t[i] = fminf(a, pb);  t[15 - i] = fminf(bb, pa); }
            else    { t[i] = fmaxf(pa, bb); t[15 - i] = fmaxf(pb, a);  }
        }
#pragma unroll
        for (int j = 8; j > 0; j >>= 1) {         // local bitonic clean
#pragma unroll
            for (int i = 0; i < 16; ++i) {
                const int l = i ^ j;
                if (l > i) {
                    const float u = t[i], v = t[l];
                    t[i] = fminf(u, v); t[l] = fmaxf(u, v);
                }
            }
        }
        // (3) xor-3 merge of the two sorted-32 halves, keep LOWER 32:
        // uniformly t[i] = min(t[i], partner3.t[15-i]) for all 4 lanes
        // (lanes 2,3 end up mirroring lanes 1,0 - same final sort).
#pragma unroll
        for (int i = 0; i < 8; ++i) {
            const float a  = t[i], bb = t[15 - i];
            const float pa = __shfl_xor(a, 3);
            const float pb = __shfl_xor(bb, 3);
            t[i]      = fminf(a, pb);
            t[15 - i] = fminf(bb, pa);
        }
        // distributed clean of the bitonic 32: dist-16 across xor-1, then local
#pragma unroll
        for (int i = 0; i < 16; ++i) {
            const float o = __shfl_xor(t[i], 1);
            t[i] = lo ? fminf(t[i], o) : fmaxf(t[i], o);
        }
#pragma unroll
        for (int j = 8; j > 0; j >>= 1) {
#pragma unroll
            for (int i = 0; i < 16; ++i) {
                const int l = i ^ j;
                if (l > i) {
                    const float u = t[i], v = t[l];
                    t[i] = fminf(u, v); t[l] = fmaxf(u, v);
                }
            }
        }
        // odd lanes hold ranks 16-31 of the lower-32; rank 26 -> local [10]
        const float cand = t[10];
        const float po   = __shfl_xor(cand, 1);
        const float thr  = (tid & 1) ? cand : po;
        const float alpha = alphap[0];

        const int  rg   = d * 4096 + h * 64 + loc;
        const long ooff = (long)b * (C * 65536) + rg;

        // epilogue: recompute attn (identical FMA order -> bitwise equal to
        // sorted values); x residual from xs; coalesced 64B-segment stores
#pragma unroll
        for (int cc = 0; cc < 16; ++cc) {
            const int ch = ch0 + cc;
            const float y1v = __half2float(y1s[ch * 64 + (loc ^ (swz7(ch) << 3))]);
            float y2 = b2[ch];
#pragma unroll
            for (int o = 0; o < C8; ++o) y2 += w2[ch * C8 + o] * hh[o];
            const float av = y1v * y2;
            const float xc = __half2float(xs[ch * 64 + (loc ^ (swz7(ch) << 3))]);
            out[ooff + (long)ch * 65536] = xc + ((av >= thr) ? alpha * av : 0.f);
        }
    }
}

extern "C" void kernel_launch(void* const* d_in, const int* in_sizes, int n_in,
                              void* d_out, int out_size, void* d_ws, size_t ws_size,
                              hipStream_t stream) {
    const float* x    = (const float*)d_in[0];
    const float* w_dw = (const float*)d_in[1];
    const float* g1   = (const float*)d_in[2];
    const float* be1  = (const float*)d_in[3];
    const float* mu1  = (const float*)d_in[4];
    const float* va1  = (const float*)d_in[5];
    const float* w1   = (const float*)d_in[6];
    const float* b1   = (const float*)d_in[7];
    const float* g2   = (const float*)d_in[8];
    const float* be2  = (const float*)d_in[9];
    const float* mu2  = (const float*)d_in[10];
    const float* va2  = (const float*)d_in[11];
    const float* w2   = (const float*)d_in[12];
    const float* b2   = (const float*)d_in[13];
    const float* alp  = (const float*)d_in[14];
    float* out = (float*)d_out;

    // grid: b(4) x d(16) x row(64) = 4096 blocks
    fused_kernel<<<4096, 256, 0, stream>>>(
        x, w_dw, g1, be1, mu1, va1, w1, b1, g2, be2, mu2, va2, w2, b2, alp, out);
}

// Round 6
// 314.926 us; speedup vs baseline: 1.2262x; 1.0410x over previous
//
#include <hip/hip_runtime.h>
#include <hip/hip_fp16.h>

#define C  64
#define C8 8
#define EPSV 1e-5f
// k = int(0.6*64) = 38 -> threshold = 38th largest = ascending index 26 of 64

__device__ __forceinline__ float silu_f(float v) {
    return v * (1.f / (1.f + __expf(-v)));
}
// channel swizzle for [ch][128] fp16 LDS tiles (chunk = 8 fp16 = 16 B).
// ch^(ch>>3) keeps the four phase-2 channel quarters (equal mod 8) on
// distinct swizzles -> worst case 2-way (free) bank aliasing.
__device__ __forceinline__ int swz7(int ch) { return (ch ^ (ch >> 3)) & 7; }

// Round-6 design:
//  - 2 output rows per block (raw halo 3x, not r5's 5x).
//  - phase 1: explicit 3-buffer register pipeline -> 12 float4 loads in
//    flight while computing (r5's 64-VGPR allocation serialized loads:
//    MLP~1, ~1 TB/s achieved BW, latency-bound at every occupancy).
//  - XCD-aware block swizzle: hw-consecutive blocks (same XCD mod 8) get
//    contiguous (b,d,hp) -> halo rows shared within one XCD's L2.
//  - phase 2: 4-lane/location split, t[16] exact distributed top-k
//    (validated r5), looped over the block's 2 rows.
//  - LDS 38.4 KB -> 4 blocks/CU; VGPR <=128 -> 16 waves/CU.
#define VAL(B, v) ((((v) & 3) == 0) ? B[(v) >> 2].x : \
                   (((v) & 3) == 1) ? B[(v) >> 2].y : \
                   (((v) & 3) == 2) ? B[(v) >> 2].z : B[(v) >> 2].w)

__global__ __launch_bounds__(256, 2) void fused_kernel(
    const float* __restrict__ x, const float* __restrict__ w_dw,
    const float* __restrict__ g1, const float* __restrict__ be1,
    const float* __restrict__ mu1, const float* __restrict__ va1,
    const float* __restrict__ w1, const float* __restrict__ b1,
    const float* __restrict__ g2, const float* __restrict__ be2,
    const float* __restrict__ mu2, const float* __restrict__ va2,
    const float* __restrict__ w2, const float* __restrict__ b2,
    const float* __restrict__ alphap, float* __restrict__ out)
{
    __shared__ __align__(16) __half xs [C * 128];  // 16 KB, x rows h0..h0+1
    __shared__ __align__(16) __half y1s[C * 128];  // 16 KB, conv out rows
    __shared__ float wt[C * 25];                   // 6.4 KB, conv weights

    // XCD swizzle (2048 % 8 == 0 -> bijective): XCD k gets logical blocks
    // [k*256,(k+1)*256) = contiguous (b, d, hp) -> halo rows L2-shared.
    const int hw  = blockIdx.x;
    const int blk = (hw & 7) * 256 + (hw >> 3);
    const int hp  = blk & 31;
    const int d   = (blk >> 5) & 15;
    const int b   = blk >> 9;
    const int h0  = hp * 2;            // output rows h0, h0+1
    const int tid = threadIdx.x;

    for (int i = tid; i < C * 25; i += 256) wt[i] = w_dw[i];
    __syncthreads();

    // ---------------- phase 1: depthwise conv rows h0..h0+1 -> y1s; x -> xs
    {
        const int c     = tid >> 2;        // 0..63
        const int strip = tid & 3;
        const int w16   = strip * 16;      // output cols w16..w16+15
        const int q     = w16 >> 2;
        const int s7    = swz7(c);

        const float scale = g1[c] * rsqrtf(va1[c] + EPSV);
        const float shift = be1[c] - mu1[c] * scale;
        const long xbase = ((long)(b * C + c) * 16 + d) * 4096;
        const float4 fzero = make_float4(0.f, 0.f, 0.f, 0.f);

        // 3-buffer register pipeline over the 6 input rows h0-2..h0+3
        float4 buf[3][6];                  // 72 VGPRs
#define LOAD_ROW(DST, J) do {                                              \
            const int r_ = h0 + (J) - 2;                                   \
            if (r_ >= 0 && r_ < 64) {                                      \
                const float4* rp_ = (const float4*)(x + xbase + r_ * 64);  \
                DST[0] = (q > 0)  ? rp_[q - 1] : fzero;                    \
                DST[1] = rp_[q];     DST[2] = rp_[q + 1];                  \
                DST[3] = rp_[q + 2]; DST[4] = rp_[q + 3];                  \
                DST[5] = (q < 12) ? rp_[q + 4] : fzero;                    \
            } else {                                                       \
                DST[0] = DST[1] = DST[2] = DST[3] = DST[4] = DST[5] = fzero;\
            }                                                              \
        } while (0)

        LOAD_ROW(buf[0], 0);
        LOAD_ROW(buf[1], 1);

        float acc[2][16];
#pragma unroll
        for (int i = 0; i < 2; ++i)
#pragma unroll
            for (int ow = 0; ow < 16; ++ow) acc[i][ow] = 0.f;

#pragma unroll
        for (int j = 0; j < 6; ++j) {      // compute row j, prefetch row j+2
            if (j < 4) { LOAD_ROW(buf[(j + 2) % 3], j + 2); }
            const float4* B = buf[j % 3];
            // stage x rows h0 (j==2) / h0+1 (j==3) to xs (cols w16..w16+15
            // are VAL indices 4..19)
            if (j == 2 || j == 3) {
                const int i = j - 2;
                const int chunkbase = i * 8 + 2 * strip;
#pragma unroll
                for (int t = 0; t < 2; ++t) {
                    const int p = (chunkbase + t) ^ s7;
                    union { __half2 hx[4]; float4 f; } u;
#pragma unroll
                    for (int m = 0; m < 4; ++m)
                        u.hx[m] = __floats2half2_rn(VAL(B, 4 + t * 8 + 2 * m),
                                                    VAL(B, 4 + t * 8 + 2 * m + 1));
                    *(float4*)&xs[c * 128 + p * 8] = u.f;
                }
            }
#pragma unroll
            for (int i = 0; i < 2; ++i) {
                if (i <= j && (j - i) <= 4) {   // kernel row kr = j - i
                    const int kr = j - i;
                    const float* wrow = &wt[c * 25 + kr * 5];
#pragma unroll
                    for (int kc = 0; kc < 5; ++kc) {
                        const float kw = wrow[kc];
#pragma unroll
                        for (int ow = 0; ow < 16; ++ow)
                            acc[i][ow] += kw * VAL(B, ow + kc + 2);
                    }
                }
            }
        }
#undef LOAD_ROW
        // BN1 + SiLU, write y1s
#pragma unroll
        for (int i = 0; i < 2; ++i) {
            float o[16];
#pragma unroll
            for (int ow = 0; ow < 16; ++ow)
                o[ow] = silu_f(acc[i][ow] * scale + shift);
            const int chunkbase = i * 8 + 2 * strip;
#pragma unroll
            for (int t = 0; t < 2; ++t) {
                const int p = (chunkbase + t) ^ s7;
                union { __half2 hx[4]; float4 f; } u;
#pragma unroll
                for (int m = 0; m < 4; ++m)
                    u.hx[m] = __floats2half2_rn(o[t * 8 + 2 * m], o[t * 8 + 2 * m + 1]);
                *(float4*)&y1s[c * 128 + p * 8] = u.f;
            }
        }
    }
    __syncthreads();

    // ---------------- phase 2: pw1+BN2+SiLU+pw2, attn, exact top-k, epilogue
    {
        const int qt   = tid & 3;          // channel quarter owned by lane
        const int loc  = tid >> 2;         // 0..63 column within a row
        const int ch0  = qt * 16;
        const bool lo  = ((tid & 1) == 0);
        const float alpha = alphap[0];

#pragma unroll
        for (int rr = 0; rr < 2; ++rr) {   // the block's two rows
            const int l128 = rr * 64 + loc;

            // pw1: lane sums its 16 channels; 2 shuffle rounds -> 64-sum
            float s1[C8];
#pragma unroll
            for (int o = 0; o < C8; ++o) s1[o] = 0.f;
#pragma unroll
            for (int cc = 0; cc < 16; ++cc) {
                const int ch = ch0 + cc;
                const float xc = __half2float(xs[ch * 128 + (l128 ^ (swz7(ch) << 3))]);
#pragma unroll
                for (int o = 0; o < C8; ++o) s1[o] += w1[o * C + ch] * xc;
            }
#pragma unroll
            for (int o = 0; o < C8; ++o) s1[o] += __shfl_xor(s1[o], 1);
#pragma unroll
            for (int o = 0; o < C8; ++o) s1[o] += __shfl_xor(s1[o], 2);
            float hh[C8];
#pragma unroll
            for (int o = 0; o < C8; ++o) {
                const float sc = g2[o] * rsqrtf(va2[o] + EPSV);
                hh[o] = silu_f((s1[o] + b1[o] - mu2[o]) * sc + be2[o]);
            }

            // attn values for this lane's 16 channels
            float t[16];
#pragma unroll
            for (int cc = 0; cc < 16; ++cc) {
                const int ch = ch0 + cc;
                const float y1v = __half2float(y1s[ch * 128 + (l128 ^ (swz7(ch) << 3))]);
                float y2 = b2[ch];
#pragma unroll
                for (int o = 0; o < C8; ++o) y2 += w2[ch * C8 + o] * hh[o];
                t[cc] = y1v * y2;
            }

            // (1) per-lane bitonic sort ascending of 16
#pragma unroll
            for (int k = 2; k <= 16; k <<= 1) {
#pragma unroll
                for (int j = k >> 1; j > 0; j >>= 1) {
#pragma unroll
                    for (int i = 0; i < 16; ++i) {
                        const int l = i ^ j;
                        if (l > i) {
                            const float u = t[i], v = t[l];
                            const float mn = fminf(u, v), mx = fmaxf(u, v);
                            if ((i & k) == 0) { t[i] = mn; t[l] = mx; }
                            else              { t[i] = mx; t[l] = mn; }
                        }
                    }
                }
            }
            // (2) xor-1 pair merge (even lane -> ranks 0-15, odd -> 16-31)
#pragma unroll
            for (int i = 0; i < 8; ++i) {
                const float a  = t[i], bb = t[15 - i];
                const float pa = __shfl_xor(a, 1);
                const float pb = __shfl_xor(bb, 1);
                if (lo) { t[i] = fminf(a, pb);  t[15 - i] = fminf(bb, pa); }
                else    { t[i] = fmaxf(pa, bb); t[15 - i] = fmaxf(pb, a);  }
            }
#pragma unroll
            for (int j = 8; j > 0; j >>= 1) {     // local bitonic clean
#pragma unroll
                for (int i = 0; i < 16; ++i) {
                    const int l = i ^ j;
                    if (l > i) {
                        const float u = t[i], v = t[l];
                        t[i] = fminf(u, v); t[l] = fmaxf(u, v);
                    }
                }
            }
            // (3) xor-3 merge of the two sorted-32 halves, keep LOWER 32
#pragma unroll
            for (int i = 0; i < 8; ++i) {
                const float a  = t[i], bb = t[15 - i];
                const float pa = __shfl_xor(a, 3);
                const float pb = __shfl_xor(bb, 3);
                t[i]      = fminf(a, pb);
                t[15 - i] = fminf(bb, pa);
            }
            // distributed clean: dist-16 across xor-1, then local
#pragma unroll
            for (int i = 0; i < 16; ++i) {
                const float o = __shfl_xor(t[i], 1);
                t[i] = lo ? fminf(t[i], o) : fmaxf(t[i], o);
            }
#pragma unroll
            for (int j = 8; j > 0; j >>= 1) {
#pragma unroll
                for (int i = 0; i < 16; ++i) {
                    const int l = i ^ j;
                    if (l > i) {
                        const float u = t[i], v = t[l];
                        t[i] = fminf(u, v); t[l] = fmaxf(u, v);
                    }
                }
            }
            // odd lanes hold ranks 16-31 of the lower-32; rank 26 -> [10]
            const float cand = t[10];
            const float po   = __shfl_xor(cand, 1);
            const float thr  = (tid & 1) ? cand : po;

            const int  rg   = d * 4096 + (h0 + rr) * 64 + loc;
            const long ooff = (long)b * (C * 65536) + rg;

            // epilogue: recompute attn (identical FMA order -> bitwise equal
            // to sorted values); x residual from xs; 64B-segment stores
#pragma unroll
            for (int cc = 0; cc < 16; ++cc) {
                const int ch = ch0 + cc;
                const float y1v = __half2float(y1s[ch * 128 + (l128 ^ (swz7(ch) << 3))]);
                float y2 = b2[ch];
#pragma unroll
                for (int o = 0; o < C8; ++o) y2 += w2[ch * C8 + o] * hh[o];
                const float av = y1v * y2;
                const float xc = __half2float(xs[ch * 128 + (l128 ^ (swz7(ch) << 3))]);
                out[ooff + (long)ch * 65536] = xc + ((av >= thr) ? alpha * av : 0.f);
            }
        }
    }
}

extern "C" void kernel_launch(void* const* d_in, const int* in_sizes, int n_in,
                              void* d_out, int out_size, void* d_ws, size_t ws_size,
                              hipStream_t stream) {
    const float* x    = (const float*)d_in[0];
    const float* w_dw = (const float*)d_in[1];
    const float* g1   = (const float*)d_in[2];
    const float* be1  = (const float*)d_in[3];
    const float* mu1  = (const float*)d_in[4];
    const float* va1  = (const float*)d_in[5];
    const float* w1   = (const float*)d_in[6];
    const float* b1   = (const float*)d_in[7];
    const float* g2   = (const float*)d_in[8];
    const float* be2  = (const float*)d_in[9];
    const float* mu2  = (const float*)d_in[10];
    const float* va2  = (const float*)d_in[11];
    const float* w2   = (const float*)d_in[12];
    const float* b2   = (const float*)d_in[13];
    const float* alp  = (const float*)d_in[14];
    float* out = (float*)d_out;

    // grid: b(4) x d(16) x row-pair(32) = 2048 blocks (XCD-swizzled in-kernel)
    fused_kernel<<<2048, 256, 0, stream>>>(
        x, w_dw, g1, be1, mu1, va1, w1, b1, g2, be2, mu2, va2, w2, b2, alp, out);
}